// Round 1
// baseline (313.902 us; speedup 1.0000x reference)
//
#include <hip/hip_runtime.h>
#include <hip/hip_bf16.h>
#include <math.h>

// Problem constants (from reference setup_inputs):
//   support [25, 2560] fp32, query [4096, 2560] fp32, n_way=5, k_shot=5
//   out [4096, 5] fp32 = -dist.reshape(4096,5,5).sum(-1)
//   dist[q][s] = || support[s] - query[q] + 1e-6 ||_2
// Strategy: dist^2 = ||s+eps||^2 - 2*(s.q + eps*sum(q)) + ||q||^2
//   -> 1 FMA per (q,s,d) element instead of 2 ops, support reuse in registers.

#define EPS 1e-6f
#define D 2560
#define NSUP 25
#define NQ 4096
#define NWAY 5
#define KSHOT 5

#define QR 4          // query rows per block (register-blocked)
#define BT 128        // block threads (2 waves); BT*4 floats per k-iter
#define KITER 5       // D / (BT*4) = 2560/512
#define NACC 108      // 100 dots + 4 sumq + 4 normq
#define STRIDE 55     // 54 columns per phase + 1 pad (55%32=23, odd -> <=2-way bank aliasing, free)

// ---- prep: ns[s] = || support[s] + eps ||^2  (25 floats into workspace) ----
__global__ void prep_kernel(const float* __restrict__ sup, float* __restrict__ ns) {
    const int s = blockIdx.x;
    const int t = threadIdx.x;  // 256 threads
    float p = 0.f;
    #pragma unroll
    for (int k = 0; k < 10; ++k) {
        float v = sup[s * D + t + 256 * k] + EPS;
        p += v * v;
    }
    __shared__ float red[256];
    red[t] = p;
    __syncthreads();
    for (int off = 128; off > 0; off >>= 1) {
        if (t < off) red[t] += red[t + off];
        __syncthreads();
    }
    if (t == 0) ns[s] = red[0];
}

// ---- main: QR query rows per block, d split across 128 threads ----
__global__ __launch_bounds__(BT, 2)
void pairwise_kernel(const float* __restrict__ q, const float* __restrict__ sup,
                     const float* __restrict__ ns, float* __restrict__ out) {
    const int t = threadIdx.x;
    const int row0 = blockIdx.x * QR;

    // acc[r*25+s] = partial dot(support[s], query[row0+r])
    // acc[100+r]  = partial sum(query[row0+r])
    // acc[104+r]  = partial ||query[row0+r]||^2
    float acc[NACC];
    #pragma unroll
    for (int i = 0; i < NACC; ++i) acc[i] = 0.f;

    #pragma unroll
    for (int k = 0; k < KITER; ++k) {
        const int idx = 4 * t + (BT * 4) * k;   // float index, 16B-aligned
        float4 q4[QR];
        #pragma unroll
        for (int r = 0; r < QR; ++r) {
            q4[r] = *reinterpret_cast<const float4*>(&q[(row0 + r) * D + idx]);
            acc[100 + r] += (q4[r].x + q4[r].y) + (q4[r].z + q4[r].w);
            acc[104 + r] += q4[r].x * q4[r].x + q4[r].y * q4[r].y
                          + q4[r].z * q4[r].z + q4[r].w * q4[r].w;
        }
        #pragma unroll
        for (int s = 0; s < NSUP; ++s) {
            const float4 a4 = *reinterpret_cast<const float4*>(&sup[s * D + idx]);
            #pragma unroll
            for (int r = 0; r < QR; ++r) {
                acc[r * NSUP + s] += a4.x * q4[r].x + a4.y * q4[r].y
                                   + a4.z * q4[r].z + a4.w * q4[r].w;
            }
        }
    }

    // ---- cross-thread reduction: LDS transpose, 2 phases of 54 columns ----
    __shared__ float buf[BT * STRIDE];
    __shared__ float fin[NACC];
    __shared__ float dist[100];

    #pragma unroll
    for (int p = 0; p < 2; ++p) {
        #pragma unroll
        for (int v = 0; v < 54; ++v) buf[t * STRIDE + v] = acc[p * 54 + v];
        __syncthreads();
        if (t < 54) {
            float s0 = 0.f, s1 = 0.f, s2 = 0.f, s3 = 0.f;
            for (int i = 0; i < BT; i += 4) {
                s0 += buf[(i + 0) * STRIDE + t];
                s1 += buf[(i + 1) * STRIDE + t];
                s2 += buf[(i + 2) * STRIDE + t];
                s3 += buf[(i + 3) * STRIDE + t];
            }
            fin[p * 54 + t] = (s0 + s1) + (s2 + s3);
        }
        __syncthreads();
    }

    // ---- epilogue: dist = sqrt(ns + ||q||^2 - 2*(dot + eps*sumq)) ----
    if (t < 100) {
        const int r = t / NSUP, s = t % NSUP;
        const float dot = fin[t];
        const float d2 = ns[s] + fin[104 + r] - 2.f * (dot + EPS * fin[100 + r]);
        dist[t] = sqrtf(fmaxf(d2, 0.f));
    }
    __syncthreads();
    if (t < QR * NWAY) {
        const int r = t / NWAY, w = t % NWAY;
        float sc = 0.f;
        #pragma unroll
        for (int j = 0; j < KSHOT; ++j) sc += dist[r * NSUP + w * KSHOT + j];
        out[(row0 + r) * NWAY + w] = -sc;
    }
}

extern "C" void kernel_launch(void* const* d_in, const int* in_sizes, int n_in,
                              void* d_out, int out_size, void* d_ws, size_t ws_size,
                              hipStream_t stream) {
    const float* support = (const float*)d_in[0];
    const float* query   = (const float*)d_in[1];
    // d_in[2]=n_way(5), d_in[3]=k_shot(5): hardcoded per setup_inputs.
    float* out = (float*)d_out;
    float* ns  = (float*)d_ws;   // 25 floats of scratch

    prep_kernel<<<NSUP, 256, 0, stream>>>(support, ns);
    pairwise_kernel<<<NQ / QR, BT, 0, stream>>>(query, support, ns, out);
}

// Round 2
// 222.687 us; speedup vs baseline: 1.4096x; 1.4096x over previous
//
#include <hip/hip_runtime.h>
#include <hip/hip_bf16.h>
#include <math.h>

// Problem constants (from reference setup_inputs):
//   support [25, 2560] fp32, query [4096, 2560] fp32, n_way=5, k_shot=5
//   out [4096, 5] fp32 = -dist.reshape(4096,5,5).sum(-1)
//   dist[q][s] = || support[s] - query[q] + 1e-6 ||_2
// Strategy: dist^2 = ||s+eps||^2 - 2*(s.q + eps*sum(q)) + ||q||^2
//   -> 1 FMA per (q,s,d) element, support reuse in registers (QR=4 rows/block).
//
// R1 post-mortem: compiler chose 128 VGPRs (4 waves/EU heuristic) and spilled
// acc[108] -> 380 MB scratch writes, 244 us. Fix: pin waves_per_eu(2,2) for a
// firm 256-VGPR budget, and stop the KITER unroll + group support loads by 5
// so peak live registers stay ~160.

#define EPS 1e-6f
#define D 2560
#define NSUP 25
#define NQ 4096
#define NWAY 5
#define KSHOT 5

#define QR 4          // query rows per block (register-blocked)
#define BT 128        // block threads (2 waves); BT*4 floats per k-iter
#define KITER 5       // D / (BT*4) = 2560/512
#define NACC 108      // 100 dots + 4 sumq + 4 normq
#define STRIDE 55     // 54 columns per phase + 1 pad (odd -> <=2-way aliasing, free)

// ---- prep: ns[s] = || support[s] + eps ||^2  (25 floats into workspace) ----
__global__ void prep_kernel(const float* __restrict__ sup, float* __restrict__ ns) {
    const int s = blockIdx.x;
    const int t = threadIdx.x;  // 256 threads
    float p = 0.f;
    #pragma unroll
    for (int k = 0; k < 10; ++k) {
        float v = sup[s * D + t + 256 * k] + EPS;
        p += v * v;
    }
    __shared__ float red[256];
    red[t] = p;
    __syncthreads();
    for (int off = 128; off > 0; off >>= 1) {
        if (t < off) red[t] += red[t + off];
        __syncthreads();
    }
    if (t == 0) ns[s] = red[0];
}

// ---- main: QR query rows per block, d split across 128 threads ----
__global__ __launch_bounds__(BT)
__attribute__((amdgpu_waves_per_eu(2, 2)))   // pin 2 waves/EU -> 256 VGPR budget, no spill
void pairwise_kernel(const float* __restrict__ q, const float* __restrict__ sup,
                     const float* __restrict__ ns, float* __restrict__ out) {
    const int t = threadIdx.x;
    const int row0 = blockIdx.x * QR;

    // acc[r*25+s] = partial dot(support[s], query[row0+r])
    // acc[100+r]  = partial sum(query[row0+r])
    // acc[104+r]  = partial ||query[row0+r]||^2
    float acc[NACC];
    #pragma unroll
    for (int i = 0; i < NACC; ++i) acc[i] = 0.f;

    #pragma unroll 1                      // do NOT unroll: bounds register pressure
    for (int k = 0; k < KITER; ++k) {
        const int idx = 4 * t + (BT * 4) * k;   // float index, 16B-aligned
        float4 q4[QR];
        #pragma unroll
        for (int r = 0; r < QR; ++r) {
            q4[r] = *reinterpret_cast<const float4*>(&q[(row0 + r) * D + idx]);
            acc[100 + r] += (q4[r].x + q4[r].y) + (q4[r].z + q4[r].w);
            acc[104 + r] += q4[r].x * q4[r].x + q4[r].y * q4[r].y
                          + q4[r].z * q4[r].z + q4[r].w * q4[r].w;
        }
        // support in 5 groups of 5: caps in-flight loads at ~20 VGPRs
        #pragma unroll
        for (int g = 0; g < 5; ++g) {
            float4 a4[5];
            #pragma unroll
            for (int j = 0; j < 5; ++j)
                a4[j] = *reinterpret_cast<const float4*>(&sup[(g * 5 + j) * D + idx]);
            #pragma unroll
            for (int j = 0; j < 5; ++j) {
                #pragma unroll
                for (int r = 0; r < QR; ++r) {
                    acc[r * NSUP + g * 5 + j] += a4[j].x * q4[r].x + a4[j].y * q4[r].y
                                               + a4[j].z * q4[r].z + a4[j].w * q4[r].w;
                }
            }
        }
    }

    // ---- cross-thread reduction: LDS transpose, 2 phases of 54 columns ----
    __shared__ float buf[BT * STRIDE];
    __shared__ float fin[NACC];
    __shared__ float dist[100];

    #pragma unroll 1
    for (int p = 0; p < 2; ++p) {
        #pragma unroll
        for (int v = 0; v < 54; ++v) buf[t * STRIDE + v] = acc[p * 54 + v];
        __syncthreads();
        if (t < 54) {
            float s0 = 0.f, s1 = 0.f, s2 = 0.f, s3 = 0.f;
            for (int i = 0; i < BT; i += 4) {
                s0 += buf[(i + 0) * STRIDE + t];
                s1 += buf[(i + 1) * STRIDE + t];
                s2 += buf[(i + 2) * STRIDE + t];
                s3 += buf[(i + 3) * STRIDE + t];
            }
            fin[p * 54 + t] = (s0 + s1) + (s2 + s3);
        }
        __syncthreads();
    }

    // ---- epilogue: dist = sqrt(ns + ||q||^2 - 2*(dot + eps*sumq)) ----
    if (t < 100) {
        const int r = t / NSUP, s = t % NSUP;
        const float dot = fin[t];
        const float d2 = ns[s] + fin[104 + r] - 2.f * (dot + EPS * fin[100 + r]);
        dist[t] = sqrtf(fmaxf(d2, 0.f));
    }
    __syncthreads();
    if (t < QR * NWAY) {
        const int r = t / NWAY, w = t % NWAY;
        float sc = 0.f;
        #pragma unroll
        for (int j = 0; j < KSHOT; ++j) sc += dist[r * NSUP + w * KSHOT + j];
        out[(row0 + r) * NWAY + w] = -sc;
    }
}

extern "C" void kernel_launch(void* const* d_in, const int* in_sizes, int n_in,
                              void* d_out, int out_size, void* d_ws, size_t ws_size,
                              hipStream_t stream) {
    const float* support = (const float*)d_in[0];
    const float* query   = (const float*)d_in[1];
    // d_in[2]=n_way(5), d_in[3]=k_shot(5): hardcoded per setup_inputs.
    float* out = (float*)d_out;
    float* ns  = (float*)d_ws;   // 25 floats of scratch

    prep_kernel<<<NSUP, 256, 0, stream>>>(support, ns);
    pairwise_kernel<<<NQ / QR, BT, 0, stream>>>(query, support, ns, out);
}

// Round 3
// 96.493 us; speedup vs baseline: 3.2531x; 2.3078x over previous
//
#include <hip/hip_runtime.h>
#include <hip/hip_bf16.h>
#include <math.h>

// Problem constants (from reference setup_inputs):
//   support [25, 2560] fp32, query [4096, 2560] fp32, n_way=5, k_shot=5
//   out [4096, 5] fp32 = -dist.reshape(4096,5,5).sum(-1)
//   dist[q][s] = || support[s] - query[q] + 1e-6 ||_2
// Strategy: dist^2 = ||s+eps||^2 - 2*(s.q + eps*sum(q)) + ||q||^2
//   -> 1 FMA per (q,s,d) element.
//
// R2 post-mortem: allocator pins VGPR=128 regardless of waves_per_eu hints;
// acc[108]/thread spills (322 MB scratch writes). R3: split the 25 supports
// across the block's 2 waves (wave0: sups 0-12, wave1: sups 12-24, 1-row
// overlap keeps indices compile-time). acc drops to 60/thread -> ~115 live
// regs, fits 128 with no scratch.

#define EPS 1e-6f
#define D 2560
#define NSUP 25
#define NQ 4096
#define NWAY 5
#define KSHOT 5

#define QR 4           // query rows per block
#define BT 128         // 2 waves; each wave covers 64 lanes * float4 = 256 floats/iter
#define KITER 10       // D / 256
#define NSL 13         // supports per wave (wave0: 0-12, wave1: 12-24)
#define NACC 60        // 52 dots + 4 sumq + 4 normq
#define STRIDE 61      // odd -> <=2-way LDS bank aliasing (free)

// ---- prep: ns[s] = || support[s] + eps ||^2  (25 floats into workspace) ----
__global__ void prep_kernel(const float* __restrict__ sup, float* __restrict__ ns) {
    const int s = blockIdx.x;
    const int t = threadIdx.x;  // 256 threads
    float p = 0.f;
    #pragma unroll
    for (int k = 0; k < 10; ++k) {
        float v = sup[s * D + t + 256 * k] + EPS;
        p += v * v;
    }
    __shared__ float red[256];
    red[t] = p;
    __syncthreads();
    for (int off = 128; off > 0; off >>= 1) {
        if (t < off) red[t] += red[t + off];
        __syncthreads();
    }
    if (t == 0) ns[s] = red[0];
}

// ---- main: QR query rows per block, supports split across the 2 waves ----
__global__ __launch_bounds__(BT, 2)
void pairwise_kernel(const float* __restrict__ q, const float* __restrict__ sup,
                     const float* __restrict__ ns, float* __restrict__ out) {
    const int t = threadIdx.x;
    const int lane = t & 63;
    const int wave = t >> 6;
    const int row0 = blockIdx.x * QR;
    const int sup_base = wave * (NSL - 1);   // 0 or 12

    // acc[r*13+j] = partial dot(support[sup_base+j], query[row0+r])
    // acc[52+r]   = partial sum(query[row0+r])      (wave0's copy is used)
    // acc[56+r]   = partial ||query[row0+r]||^2     (wave0's copy is used)
    float acc[NACC];
    #pragma unroll
    for (int i = 0; i < NACC; ++i) acc[i] = 0.f;

    #pragma unroll 1                      // do NOT unroll: bounds register pressure
    for (int k = 0; k < KITER; ++k) {
        const int idx = 4 * lane + 256 * k;     // float index, 16B-aligned
        float4 q4[QR];
        #pragma unroll
        for (int r = 0; r < QR; ++r)
            q4[r] = *reinterpret_cast<const float4*>(&q[(row0 + r) * D + idx]);
        #pragma unroll
        for (int r = 0; r < QR; ++r) {
            acc[52 + r] += (q4[r].x + q4[r].y) + (q4[r].z + q4[r].w);
            acc[56 + r] += q4[r].x * q4[r].x + q4[r].y * q4[r].y
                         + q4[r].z * q4[r].z + q4[r].w * q4[r].w;
        }
        // 13 supports in groups of 4 (4,4,4,1): caps in-flight loads at 16 VGPRs
        #pragma unroll
        for (int g = 0; g < NSL; g += 4) {
            const int ge = (g + 4 < NSL) ? g + 4 : NSL;
            float4 a4[4];
            #pragma unroll
            for (int j = g; j < ge; ++j)
                a4[j - g] = *reinterpret_cast<const float4*>(&sup[(sup_base + j) * D + idx]);
            #pragma unroll
            for (int j = g; j < ge; ++j) {
                #pragma unroll
                for (int r = 0; r < QR; ++r) {
                    acc[r * NSL + j] += a4[j - g].x * q4[r].x + a4[j - g].y * q4[r].y
                                      + a4[j - g].z * q4[r].z + a4[j - g].w * q4[r].w;
                }
            }
        }
    }

    // ---- cross-thread reduction: LDS transpose, per-wave columns ----
    __shared__ float buf[BT * STRIDE];   // 31232 B
    __shared__ float red0[NACC];         // wave0 sums (sups 0-12 + q stats)
    __shared__ float red1[NACC];         // wave1 sums (sups 12-24)
    __shared__ float dist[100];

    #pragma unroll
    for (int v = 0; v < NACC; ++v) buf[t * STRIDE + v] = acc[v];
    __syncthreads();

    if (lane < NACC) {
        const int base = wave * 64;
        float s0 = 0.f, s1 = 0.f, s2 = 0.f, s3 = 0.f;
        for (int i = 0; i < 64; i += 4) {
            s0 += buf[(base + i + 0) * STRIDE + lane];
            s1 += buf[(base + i + 1) * STRIDE + lane];
            s2 += buf[(base + i + 2) * STRIDE + lane];
            s3 += buf[(base + i + 3) * STRIDE + lane];
        }
        const float tot = (s0 + s1) + (s2 + s3);
        if (wave == 0) red0[lane] = tot;
        else           red1[lane] = tot;
    }
    __syncthreads();

    // ---- epilogue: dist = sqrt(ns + ||q||^2 - 2*(dot + eps*sumq)) ----
    if (t < 100) {
        const int r = t / NSUP, s = t % NSUP;
        const float dot = (s < NSL) ? red0[r * NSL + s] : red1[r * NSL + (s - (NSL - 1))];
        const float d2 = ns[s] + red0[56 + r] - 2.f * (dot + EPS * red0[52 + r]);
        dist[t] = sqrtf(fmaxf(d2, 0.f));
    }
    __syncthreads();
    if (t < QR * NWAY) {
        const int r = t / NWAY, w = t % NWAY;
        float sc = 0.f;
        #pragma unroll
        for (int j = 0; j < KSHOT; ++j) sc += dist[r * NSUP + w * KSHOT + j];
        out[(row0 + r) * NWAY + w] = -sc;
    }
}

extern "C" void kernel_launch(void* const* d_in, const int* in_sizes, int n_in,
                              void* d_out, int out_size, void* d_ws, size_t ws_size,
                              hipStream_t stream) {
    const float* support = (const float*)d_in[0];
    const float* query   = (const float*)d_in[1];
    // d_in[2]=n_way(5), d_in[3]=k_shot(5): hardcoded per setup_inputs.
    float* out = (float*)d_out;
    float* ns  = (float*)d_ws;   // 25 floats of scratch

    prep_kernel<<<NSUP, 256, 0, stream>>>(support, ns);
    pairwise_kernel<<<NQ / QR, BT, 0, stream>>>(query, support, ns, out);
}